// Round 9
// baseline (883.377 us; speedup 1.0000x reference)
//
#include <hip/hip_runtime.h>
#include <hip/hip_bf16.h>
#include <stdint.h>

// Problem constants (fixed by reference setup)
#define NATOMS 16384          // B*NPB = 512*32
#define ETOT   327680         // NATOMS*K (K=20 neighbors)
#define NLAYER 4

typedef __hip_bfloat16 bf16;
using bf16x8 = __attribute__((ext_vector_type(8))) short;   // MFMA A/B frag (4 VGPRs)
using bf16x4 = __attribute__((ext_vector_type(4))) short;   // 8B packed bf16
using f32x4  = __attribute__((ext_vector_type(4))) float;   // MFMA C/D frag

#define LDSF_STRIDE 260   // f32 words per barrier-bridge row (gemm_k)

__device__ __forceinline__ float bf2f(short s) {
  union { float f; unsigned u; } x; x.u = ((unsigned)(unsigned short)s) << 16; return x.f;
}
__device__ __forceinline__ short f2bf(float f) {
  bf16 b = __float2bfloat16(f);
  return *(short*)&b;
}

// ---------------------------------------------------------------------------
// async global->LDS 16B (used by gemm_k only)
// ---------------------------------------------------------------------------
__device__ __forceinline__ void async16(const void* g, void* l) {
  __builtin_amdgcn_global_load_lds(
      (const __attribute__((address_space(1))) unsigned int*)g,
      (__attribute__((address_space(3))) unsigned int*)l, 16, 0, 0);
}

// ---------------------------------------------------------------------------
// Tiled bf16 MFMA GEMM: C[MT x 256] per block, 4 waves (64 cols each),
// K in chunks of 64.  MT in {64,128}.  (unchanged from round 5)
// ---------------------------------------------------------------------------
template<int KTOT, int EPI, int MT>
__global__ void __launch_bounds__(256, 2)
gemm_k(const bf16* A, const bf16* A2, const bf16* B,
       bf16* Obf, int ldOut, const float* bias,
       float* Hf, bf16* Hbf)
{
  __shared__ __align__(16) char smem[49152];   // A tile @0 (<=16KB), B tile 32KB @16384
  __shared__ float s_bias[256];

  const int tid  = threadIdx.x;
  const int w    = tid >> 6;        // wave 0..3 (owns 64-col slice)
  const int lane = tid & 63;
  const int q    = lane >> 4;       // quad
  const int t16  = lane & 15;
  const size_t row0 = (size_t)blockIdx.x * MT;
  const int ncol0 = blockIdx.y * 256;
  constexpr int MI = MT / 16;       // row-tiles per wave
  constexpr int AI = MT / 32;       // A-stage issues per wave

  if constexpr (EPI == 2 || EPI == 4) s_bias[tid] = bias[tid];

  f32x4 acc[MI][4] = {};

  constexpr int NCHUNK = KTOT / 64;
  for (int kc = 0; kc < NCHUNK; ++kc) {
    const int k0 = kc * 64;
    const bf16* Asrc; int k0e; int ldA;
    if constexpr (KTOT == 512) {            // node MLP1: concat [h | agg]
      if (k0 < 256) { Asrc = A;  k0e = k0;       }
      else          { Asrc = A2; k0e = k0 - 256; }
      ldA = 256;
    } else {
      Asrc = A; k0e = k0; ldA = KTOT;
    }

    __syncthreads();
    #pragma unroll
    for (int ii = 0; ii < AI; ++ii) {
      int i = w * AI + ii;
      int f = i * 64 + lane;
      int m = f >> 3, s = f & 7;
      int ko = s ^ (m & 7);
      const bf16* g = Asrc + (row0 + (size_t)m) * ldA + (size_t)(k0e + ko * 8);
      async16(g, smem + i * 1024);
    }
    #pragma unroll
    for (int ii = 0; ii < 8; ++ii) {
      int i = w * 8 + ii;
      int f = i * 64 + lane;
      int n = f >> 3, s = f & 7;
      int ko = s ^ (n & 7);
      const bf16* g = B + (size_t)(ncol0 + n) * KTOT + (size_t)(k0 + ko * 8);
      async16(g, smem + 16384 + i * 1024);
    }
    __syncthreads();

    #pragma unroll
    for (int ks = 0; ks < 2; ++ks) {
      bf16x8 av[MI]; bf16x8 bv[4];
      const int ko = q + 4 * ks;
      #pragma unroll
      for (int mi = 0; mi < MI; ++mi) {
        int m = 16 * mi + t16;
        int f = m * 8 + (ko ^ (m & 7));
        av[mi] = *(const bf16x8*)(smem + f * 16);
      }
      #pragma unroll
      for (int ni = 0; ni < 4; ++ni) {
        int n = 64 * w + 16 * ni + t16;
        int f = n * 8 + (ko ^ (n & 7));
        bv[ni] = *(const bf16x8*)(smem + 16384 + f * 16);
      }
      #pragma unroll
      for (int mi = 0; mi < MI; ++mi)
        #pragma unroll
        for (int ni = 0; ni < 4; ++ni)
          acc[mi][ni] = __builtin_amdgcn_mfma_f32_16x16x32_bf16(
              av[mi], bv[ni], acc[mi][ni], 0, 0, 0);
    }
  }

  // ---- epilogue via LDS transpose bridge ----
  float* lds_f = (float*)smem;
  #pragma unroll
  for (int mi = 0; mi < MI; ++mi) {
    __syncthreads();
    #pragma unroll
    for (int ni = 0; ni < 4; ++ni)
      #pragma unroll
      for (int r = 0; r < 4; ++r)
        lds_f[(4 * q + r) * LDSF_STRIDE + 64 * w + 16 * ni + t16] = acc[mi][ni][r];
    __syncthreads();
    #pragma unroll
    for (int j = 0; j < 2; ++j) {
      int task = tid + 256 * j;
      int rr = task >> 5, cg = task & 31;
      int c0 = cg * 8;
      size_t rg = row0 + 16 * mi + rr;
      f32x4 v0 = *(const f32x4*)(lds_f + rr * LDSF_STRIDE + c0);
      f32x4 v1 = *(const f32x4*)(lds_f + rr * LDSF_STRIDE + c0 + 4);
      float v[8] = {v0[0], v0[1], v0[2], v0[3], v1[0], v1[1], v1[2], v1[3]};
      if constexpr (EPI == 0) {
        bf16x8 o;
        #pragma unroll
        for (int k = 0; k < 8; ++k) o[k] = f2bf(v[k]);
        *(bf16x8*)(Obf + rg * ldOut + (ncol0 + c0)) = o;
      } else if constexpr (EPI == 2) {
        bf16x8 o;
        #pragma unroll
        for (int k = 0; k < 8; ++k) o[k] = f2bf(fmaxf(v[k] + s_bias[c0 + k], 0.f));
        *(bf16x8*)(Obf + rg * 256 + c0) = o;
      } else {  // EPI == 4: h_new = 2*h + (acc + bias)
        f32x4 h0 = *(const f32x4*)(Hf + rg * 256 + c0);
        f32x4 h1 = *(const f32x4*)(Hf + rg * 256 + c0 + 4);
        float hh[8] = {h0[0], h0[1], h0[2], h0[3], h1[0], h1[1], h1[2], h1[3]};
        bf16x8 o; f32x4 n0, n1;
        #pragma unroll
        for (int k = 0; k < 8; ++k) {
          float hn = 2.f * hh[k] + v[k] + s_bias[c0 + k];
          o[k] = f2bf(hn);
          if (k < 4) n0[k] = hn; else n1[k - 4] = hn;
        }
        *(f32x4*)(Hf + rg * 256 + c0)     = n0;
        *(f32x4*)(Hf + rg * 256 + c0 + 4) = n1;
        *(bf16x8*)(Hbf + rg * 256 + c0) = o;
      }
    }
  }
}

// ---------------------------------------------------------------------------
// Building-block edge pipeline v3: one block per building block.
// Latency-chain fixes vs v2 (r8):
//  * ALL edge meta (rc, rad) precomputed before the loop -> global eidx/pos
//    latency out of the chunk chain; s_rc packed to 2B.
//  * Gaussian B-frags computed in registers, streamed per-ci (no gauss LDS
//    tile, no gauss barriers; exps overlap MFMA issue).
//  * We2T fragments: kc 0-1 persistent in VGPRs (loaded once), kc 2-3
//    prefetched per chunk right after GEMM1 (consumed ~1000cy later).
//  * 2 barriers per chunk (pre/post phase-2) + 1 upfront = 17 vs 32.
// LDS: window 33280 | m1 40960 | rc 1280 | rad 2560 | b1 1024 | wrad 1024
//      = 80128 -> 2 blocks/CU.
// ---------------------------------------------------------------------------
#define BBPITCH 1040       // window row pitch bytes
#define M1O     33280      // m1 tile offset: 80 rows x 512 B
#define RCO     74240      // packed (row|col<<8) ushort[640]
#define RADO    75520      // radial float[640]
#define B1O     78080      // be1 float[256]
#define WRO     79104      // wrad float[256]

__global__ void __launch_bounds__(256, 2)
bb_edge_fused(const bf16* WgT_l, const bf16* We2T_l, const float* off,
              const float* pos, const int* eidx, const bf16* Prc,
              const float* be1, const float* wrad, const float* be2, bf16* Agg)
{
  __shared__ __align__(16) char smem[80128];
  unsigned short* s_rc  = (unsigned short*)(smem + RCO);
  float*          s_rad = (float*)(smem + RADO);
  float*          s_b1  = (float*)(smem + B1O);
  float*          s_wr  = (float*)(smem + WRO);

  const int tid  = threadIdx.x;
  const int w    = tid >> 6;
  const int lane = tid & 63;
  const int q    = lane >> 4;
  const int t16  = lane & 15;
  const int bb   = blockIdx.x;
  const int node0 = bb * 32;
  const int ebase = bb * 640;

  // ---- persistent per-lane constants ----
  float offk[2][8];
  #pragma unroll
  for (int ks = 0; ks < 2; ++ks) {
    f32x4 o0 = *(const f32x4*)(off + (q + 4 * ks) * 8);
    f32x4 o1 = *(const f32x4*)(off + (q + 4 * ks) * 8 + 4);
    #pragma unroll
    for (int j = 0; j < 4; ++j) { offk[ks][j] = o0[j]; offk[ks][4 + j] = o1[j]; }
  }
  float b2v[4];
  #pragma unroll
  for (int ni = 0; ni < 4; ++ni) b2v[ni] = be2[64 * w + 16 * ni + t16];

  // We2T persistent fragments for kc = 0,1 (64 VGPR)
  bf16x8 bvp[2][4][2];
  #pragma unroll
  for (int kc = 0; kc < 2; ++kc)
    #pragma unroll
    for (int ni = 0; ni < 4; ++ni)
      #pragma unroll
      for (int ks = 0; ks < 2; ++ks) {
        int n = 64 * w + 16 * ni + t16;
        bvp[kc][ni][ks] =
            *(const bf16x8*)(We2T_l + (size_t)n * 256 + kc * 64 + (q + 4 * ks) * 8);
      }

  // ---- Prc window -> LDS (32 rows x 1024 B, coalesced, once) ----
  {
    int row = tid >> 3, seg = tid & 7;
    const bf16* src = Prc + (size_t)(node0 + row) * 512 + seg * 64;
    char* dst = smem + row * BBPITCH + seg * 128;
    #pragma unroll
    for (int j = 0; j < 8; ++j)
      *(bf16x8*)(dst + j * 16) = *(const bf16x8*)(src + j * 8);
  }
  // ---- all-edge meta (640 edges) ----
  for (int i = tid; i < 640; i += 256) {
    int e = ebase + i;
    int r = eidx[e], cc = eidx[ETOT + e];
    float dx = pos[cc * 3 + 0] - pos[r * 3 + 0];
    float dy = pos[cc * 3 + 1] - pos[r * 3 + 1];
    float dz = pos[cc * 3 + 2] - pos[r * 3 + 2];
    float d2 = dx * dx + dy * dy + dz * dz;
    s_rc[i]  = (unsigned short)((r & 31) | ((cc & 31) << 8));
    s_rad[i] = 0.01f * d2;
  }
  s_b1[tid] = be1[tid];
  s_wr[tid] = wrad[tid];
  __syncthreads();                           // everything staged

  const float GC = -0.5f / ((5.0f / 63.0f) * (5.0f / 63.0f));

  for (int c = 0; c < 8; ++c) {
    // ---- wgf reload (L2-hot, 8x16B) ----
    bf16x8 wgf[4][2];
    #pragma unroll
    for (int fi = 0; fi < 4; ++fi)
      #pragma unroll
      for (int ks = 0; ks < 2; ++ks) {
        int feat = 64 * w + 16 * fi + t16;
        wgf[fi][ks] = *(const bf16x8*)(WgT_l + (size_t)feat * 64 + (q + 4 * ks) * 8);
      }

    // ---- Phase 1: gauss-in-reg (streamed) + GEMM1: D[feature][edge] ----
    f32x4 acc[5][4] = {};                    // phase1: acc[ci][fi]; phase3: acc[mi][ni]
    #pragma unroll
    for (int ci = 0; ci < 5; ++ci) {
      int eg = 80 * c + 16 * ci + t16;
      float d = 10.f * sqrtf(s_rad[eg]);     // rad = 0.01 d^2
      bf16x8 gv[2];
      #pragma unroll
      for (int ks = 0; ks < 2; ++ks)
        #pragma unroll
        for (int j = 0; j < 8; ++j) {
          float t = d - offk[ks][j];
          gv[ks][j] = f2bf(__expf(GC * t * t));
        }
      #pragma unroll
      for (int ks = 0; ks < 2; ++ks)
        #pragma unroll
        for (int fi = 0; fi < 4; ++fi)
          acc[ci][fi] = __builtin_amdgcn_mfma_f32_16x16x32_bf16(
              wgf[fi][ks], gv[ks], acc[ci][fi], 0, 0, 0);
    }

    // ---- prefetch We2T kc = 2,3 (consumed in GEMM2, ~1000cy later) ----
    bf16x8 bvl[2][4][2];
    #pragma unroll
    for (int kc = 0; kc < 2; ++kc)
      #pragma unroll
      for (int ni = 0; ni < 4; ++ni)
        #pragma unroll
        for (int ks = 0; ks < 2; ++ks) {
          int n = 64 * w + 16 * ni + t16;
          bvl[kc][ni][ks] = *(const bf16x8*)(We2T_l + (size_t)n * 256 +
                                             (kc + 2) * 64 + (q + 4 * ks) * 8);
        }

    __syncthreads();                         // (#1) all waves' GEMM2(c-1) reads done
    // ---- Phase 2: epilogue -> m1 LDS tile (wave-private column band) ----
    #pragma unroll
    for (int ci = 0; ci < 5; ++ci) {
      int e = 16 * ci + t16;
      int eg = 80 * c + e;
      int rc = s_rc[eg];
      int rl = rc & 31, cl = (rc >> 8) & 31;
      float rad = s_rad[eg];
      #pragma unroll
      for (int fi = 0; fi < 4; ++fi) {
        int fb = 64 * w + 16 * fi + 4 * q;
        f32x4 tb = *(const f32x4*)(s_b1 + fb);
        f32x4 tw = *(const f32x4*)(s_wr + fb);
        bf16x4 pr = *(const bf16x4*)(smem + rl * BBPITCH + fb * 2);
        bf16x4 pc = *(const bf16x4*)(smem + cl * BBPITCH + 512 + fb * 2);
        bf16x4 o;
        #pragma unroll
        for (int r = 0; r < 4; ++r) {
          float val = acc[ci][fi][r] + tb[r] + rad * tw[r]
                    + bf2f(pr[r]) + bf2f(pc[r]);
          o[r] = f2bf(fmaxf(val, 0.f));
        }
        int u = (16 * w + 4 * fi + q) ^ (e & 14);
        *(bf16x4*)(smem + M1O + e * 512 + u * 8) = o;
      }
    }
    __syncthreads();                         // (#2) m1 complete

    // ---- Phase 3: GEMM2 (K=256), A = LDS m1, B = VGPR fragments ----
    #pragma unroll
    for (int ci = 0; ci < 5; ++ci)
      #pragma unroll
      for (int ni = 0; ni < 4; ++ni)
        acc[ci][ni] = f32x4{0.f, 0.f, 0.f, 0.f};
    #pragma unroll
    for (int kc = 0; kc < 4; ++kc) {
      #pragma unroll
      for (int ks = 0; ks < 2; ++ks) {
        const int ko = q + 4 * ks;
        bf16x8 av[5];
        #pragma unroll
        for (int mi = 0; mi < 5; ++mi) {
          int e = 16 * mi + t16;
          int ub = (2 * (8 * kc + ko)) ^ (t16 & 14);
          av[mi] = *(const bf16x8*)(smem + M1O + e * 512 + ub * 8);
        }
        #pragma unroll
        for (int mi = 0; mi < 5; ++mi)
          #pragma unroll
          for (int ni = 0; ni < 4; ++ni)
            acc[mi][ni] = __builtin_amdgcn_mfma_f32_16x16x32_bf16(
                av[mi],
                (kc < 2) ? bvp[kc][ni][ks] : bvl[kc - 2][ni][ks],
                acc[mi][ni], 0, 0, 0);
      }
    }

    // ---- Phase 4: register relu + segment-sum -> Agg ----
    #pragma unroll
    for (int ni = 0; ni < 4; ++ni) {
      float b = b2v[ni];
      float pp[5];
      #pragma unroll
      for (int mi = 0; mi < 5; ++mi) {
        float s = 0.f;
        #pragma unroll
        for (int r = 0; r < 4; ++r) s += fmaxf(acc[mi][ni][r] + b, 0.f);
        pp[mi] = s;
      }
      #pragma unroll
      for (int nn = 0; nn < 4; ++nn) {
        float s = 0.f;
        #pragma unroll
        for (int mi = 0; mi < 5; ++mi) {
          int g = 4 * mi + q;
          if (g >= 5 * nn && g <= 5 * nn + 4) s += pp[mi];
        }
        s += __shfl_xor(s, 16, 64);
        s += __shfl_xor(s, 32, 64);
        if (q == nn)
          Agg[(size_t)(node0 + c * 4 + nn) * 256 + 64 * w + 16 * ni + t16] =
              __float2bfloat16(s);
      }
    }
  }
}

// ---------------------------------------------------------------------------
// Prep kernels: weight repack/transpose to bf16 [n][k] layouts, once per call
// ---------------------------------------------------------------------------
__global__ void wrct_kernel(const float* We1, bf16* WrcT) {
  int idx = blockIdx.x * 256 + threadIdx.x;         // L*512*256
  int k = idx & 255, np = (idx >> 8) & 511, l = idx >> 17;
  float v = (np < 256)
      ? We1[((size_t)l * 577 + k) * 256 + np]
      : We1[((size_t)l * 577 + 256 + k) * 256 + (np - 256)];
  WrcT[idx] = __float2bfloat16(v);
}
__global__ void wgt_kernel(const float* We1, bf16* WgT) {
  int idx = blockIdx.x * 256 + threadIdx.x;         // L*256*64
  int k = idx & 63, n = (idx >> 6) & 255, l = idx >> 14;
  WgT[idx] = __float2bfloat16(We1[((size_t)l * 577 + 513 + k) * 256 + n]);
}
__global__ void wrad_kernel(const float* We1, float* wrad) {
  int idx = blockIdx.x * 256 + threadIdx.x;         // L*256
  int n = idx & 255, l = idx >> 8;
  wrad[idx] = We1[((size_t)l * 577 + 512) * 256 + n];
}
__global__ void trans_kernel(const float* src, bf16* dst, int R, int C) {
  int idx = blockIdx.x * 256 + threadIdx.x;         // L*C*R, dst [l][n][k]
  int k = idx % R, rest = idx / R;
  int n = rest % C, l = rest / C;
  dst[idx] = __float2bfloat16(src[((size_t)l * R + k) * C + n]);
}

__global__ void h0_kernel(const int* types, const float* emb, float* h, bf16* hbf) {
  int i = blockIdx.x, c = threadIdx.x;
  float v = emb[(size_t)(types[i] - 1) * 256 + c];
  h[(size_t)i * 256 + c] = v;
  hbf[(size_t)i * 256 + c] = __float2bfloat16(v);
}

// global mean pool over 32 atoms per building block
__global__ void pool_kernel(const float* h, float* out) {
  int b = blockIdx.x, c = threadIdx.x;
  float s = 0.f;
  #pragma unroll
  for (int j = 0; j < 32; ++j) s += h[((size_t)b * 32 + j) * 256 + c];
  out[(size_t)b * 256 + c] = s * (1.0f / 32.0f);
}

// ---------------------------------------------------------------------------
extern "C" void kernel_launch(void* const* d_in, const int* in_sizes, int n_in,
                              void* d_out, int out_size, void* d_ws, size_t ws_size,
                              hipStream_t stream) {
  const float* pos   = (const float*)d_in[0];
  const int*   atype = (const int*)  d_in[1];
  const int*   eidx  = (const int*)  d_in[2];
  const float* emb   = (const float*)d_in[4];
  const float* off   = (const float*)d_in[5];
  const float* We1   = (const float*)d_in[6];
  const float* be1   = (const float*)d_in[7];
  const float* We2   = (const float*)d_in[8];
  const float* be2   = (const float*)d_in[9];
  const float* Wn1   = (const float*)d_in[10];
  const float* bn1   = (const float*)d_in[11];
  const float* Wn2   = (const float*)d_in[12];
  const float* bn2   = (const float*)d_in[13];
  float* out = (float*)d_out;

  // ---- workspace carve (256B aligned, ~61 MB total; ws_size = 256 MiB) ----
  size_t o = 0;
  auto carve = [&](size_t bytes) {
    void* p = (char*)d_ws + o;
    o += (bytes + 255) & ~(size_t)255;
    return p;
  };
  float* h     = (float*)carve((size_t)NATOMS * 256 * 4);   // 16 MB
  bf16*  hbf   = (bf16*) carve((size_t)NATOMS * 256 * 2);   //  8 MB
  bf16*  Prc   = (bf16*) carve((size_t)NATOMS * 512 * 2);   // 16 MB
  bf16*  aggbf = (bf16*) carve((size_t)NATOMS * 256 * 2);   //  8 MB (agg, then nMLP1 out)
  bf16*  WrcT  = (bf16*) carve((size_t)NLAYER * 512 * 256 * 2);
  bf16*  WgT   = (bf16*) carve((size_t)NLAYER * 256 * 64 * 2);
  bf16*  We2T  = (bf16*) carve((size_t)NLAYER * 256 * 256 * 2);
  bf16*  Wn1T  = (bf16*) carve((size_t)NLAYER * 256 * 512 * 2);
  bf16*  Wn2T  = (bf16*) carve((size_t)NLAYER * 256 * 256 * 2);
  float* wradp = (float*)carve((size_t)NLAYER * 256 * 4);

  // ---- prep: weights -> bf16 transposed, h0 gather ----
  wrct_kernel<<<2048, 256, 0, stream>>>(We1, WrcT);
  wgt_kernel <<< 256, 256, 0, stream>>>(We1, WgT);
  wrad_kernel<<<   4, 256, 0, stream>>>(We1, wradp);
  trans_kernel<<<1024, 256, 0, stream>>>(We2, We2T, 256, 256);
  trans_kernel<<<2048, 256, 0, stream>>>(Wn1, Wn1T, 512, 256);
  trans_kernel<<<1024, 256, 0, stream>>>(Wn2, Wn2T, 256, 256);
  h0_kernel  <<<NATOMS, 256, 0, stream>>>(atype, emb, h, hbf);

  // ---- layers ----
  for (int l = 0; l < NLAYER; ++l) {
    // Prc[N,512] = h @ [We1_r | We1_c]
    gemm_k<256, 0, 64><<<dim3(256, 2), 256, 0, stream>>>(
        hbf, nullptr, WrcT + (size_t)l * 512 * 256, Prc, 512, nullptr,
        nullptr, nullptr);
    // agg = segment_sum(relu(MLP2(MLP1(edges)))) — one block per building block
    bb_edge_fused<<<512, 256, 0, stream>>>(
        WgT + (size_t)l * 256 * 64, We2T + (size_t)l * 256 * 256, off, pos,
        eidx, Prc, be1 + l * 256, wradp + l * 256, be2 + l * 256, aggbf);
    // t[N,256] = relu([h|agg] @ Wn1 + bn1), in-place into aggbf
    gemm_k<512, 2, 64><<<dim3(256, 1), 256, 0, stream>>>(
        hbf, aggbf, Wn1T + (size_t)l * 256 * 512, aggbf, 256, bn1 + l * 256,
        nullptr, nullptr);
    // h = 2h + (t @ Wn2 + bn2)
    gemm_k<256, 4, 64><<<dim3(256, 1), 256, 0, stream>>>(
        aggbf, nullptr, Wn2T + (size_t)l * 256 * 256, nullptr, 0, bn2 + l * 256,
        h, hbf);
  }

  pool_kernel<<<512, 256, 0, stream>>>(h, out);
}

// Round 10
// 761.552 us; speedup vs baseline: 1.1600x; 1.1600x over previous
//
#include <hip/hip_runtime.h>
#include <hip/hip_bf16.h>
#include <stdint.h>

// Problem constants (fixed by reference setup)
#define NATOMS 16384          // B*NPB = 512*32
#define ETOT   327680         // NATOMS*K (K=20 neighbors)
#define NLAYER 4

typedef __hip_bfloat16 bf16;
using bf16x8 = __attribute__((ext_vector_type(8))) short;   // MFMA A/B frag (4 VGPRs)
using bf16x4 = __attribute__((ext_vector_type(4))) short;   // 8B packed bf16
using f32x4  = __attribute__((ext_vector_type(4))) float;   // MFMA C/D frag

#define LDSF_STRIDE 260   // f32 words per barrier-bridge row (gemm_k)

__device__ __forceinline__ float bf2f(short s) {
  union { float f; unsigned u; } x; x.u = ((unsigned)(unsigned short)s) << 16; return x.f;
}
__device__ __forceinline__ short f2bf(float f) {
  bf16 b = __float2bfloat16(f);
  return *(short*)&b;
}

// ---------------------------------------------------------------------------
// async global->LDS 16B (used by gemm_k only)
// ---------------------------------------------------------------------------
__device__ __forceinline__ void async16(const void* g, void* l) {
  __builtin_amdgcn_global_load_lds(
      (const __attribute__((address_space(1))) unsigned int*)g,
      (__attribute__((address_space(3))) unsigned int*)l, 16, 0, 0);
}

// ---------------------------------------------------------------------------
// Tiled bf16 MFMA GEMM: C[MT x 256] per block, 4 waves (64 cols each),
// K in chunks of 64.  MT in {64,128}.  (unchanged from round 5)
// ---------------------------------------------------------------------------
template<int KTOT, int EPI, int MT>
__global__ void __launch_bounds__(256, 2)
gemm_k(const bf16* A, const bf16* A2, const bf16* B,
       bf16* Obf, int ldOut, const float* bias,
       float* Hf, bf16* Hbf)
{
  __shared__ __align__(16) char smem[49152];   // A tile @0 (<=16KB), B tile 32KB @16384
  __shared__ float s_bias[256];

  const int tid  = threadIdx.x;
  const int w    = tid >> 6;        // wave 0..3 (owns 64-col slice)
  const int lane = tid & 63;
  const int q    = lane >> 4;       // quad
  const int t16  = lane & 15;
  const size_t row0 = (size_t)blockIdx.x * MT;
  const int ncol0 = blockIdx.y * 256;
  constexpr int MI = MT / 16;       // row-tiles per wave
  constexpr int AI = MT / 32;       // A-stage issues per wave

  if constexpr (EPI == 2 || EPI == 4) s_bias[tid] = bias[tid];

  f32x4 acc[MI][4] = {};

  constexpr int NCHUNK = KTOT / 64;
  for (int kc = 0; kc < NCHUNK; ++kc) {
    const int k0 = kc * 64;
    const bf16* Asrc; int k0e; int ldA;
    if constexpr (KTOT == 512) {            // node MLP1: concat [h | agg]
      if (k0 < 256) { Asrc = A;  k0e = k0;       }
      else          { Asrc = A2; k0e = k0 - 256; }
      ldA = 256;
    } else {
      Asrc = A; k0e = k0; ldA = KTOT;
    }

    __syncthreads();
    #pragma unroll
    for (int ii = 0; ii < AI; ++ii) {
      int i = w * AI + ii;
      int f = i * 64 + lane;
      int m = f >> 3, s = f & 7;
      int ko = s ^ (m & 7);
      const bf16* g = Asrc + (row0 + (size_t)m) * ldA + (size_t)(k0e + ko * 8);
      async16(g, smem + i * 1024);
    }
    #pragma unroll
    for (int ii = 0; ii < 8; ++ii) {
      int i = w * 8 + ii;
      int f = i * 64 + lane;
      int n = f >> 3, s = f & 7;
      int ko = s ^ (n & 7);
      const bf16* g = B + (size_t)(ncol0 + n) * KTOT + (size_t)(k0 + ko * 8);
      async16(g, smem + 16384 + i * 1024);
    }
    __syncthreads();

    #pragma unroll
    for (int ks = 0; ks < 2; ++ks) {
      bf16x8 av[MI]; bf16x8 bv[4];
      const int ko = q + 4 * ks;
      #pragma unroll
      for (int mi = 0; mi < MI; ++mi) {
        int m = 16 * mi + t16;
        int f = m * 8 + (ko ^ (m & 7));
        av[mi] = *(const bf16x8*)(smem + f * 16);
      }
      #pragma unroll
      for (int ni = 0; ni < 4; ++ni) {
        int n = 64 * w + 16 * ni + t16;
        int f = n * 8 + (ko ^ (n & 7));
        bv[ni] = *(const bf16x8*)(smem + 16384 + f * 16);
      }
      #pragma unroll
      for (int mi = 0; mi < MI; ++mi)
        #pragma unroll
        for (int ni = 0; ni < 4; ++ni)
          acc[mi][ni] = __builtin_amdgcn_mfma_f32_16x16x32_bf16(
              av[mi], bv[ni], acc[mi][ni], 0, 0, 0);
    }
  }

  // ---- epilogue via LDS transpose bridge ----
  float* lds_f = (float*)smem;
  #pragma unroll
  for (int mi = 0; mi < MI; ++mi) {
    __syncthreads();
    #pragma unroll
    for (int ni = 0; ni < 4; ++ni)
      #pragma unroll
      for (int r = 0; r < 4; ++r)
        lds_f[(4 * q + r) * LDSF_STRIDE + 64 * w + 16 * ni + t16] = acc[mi][ni][r];
    __syncthreads();
    #pragma unroll
    for (int j = 0; j < 2; ++j) {
      int task = tid + 256 * j;
      int rr = task >> 5, cg = task & 31;
      int c0 = cg * 8;
      size_t rg = row0 + 16 * mi + rr;
      f32x4 v0 = *(const f32x4*)(lds_f + rr * LDSF_STRIDE + c0);
      f32x4 v1 = *(const f32x4*)(lds_f + rr * LDSF_STRIDE + c0 + 4);
      float v[8] = {v0[0], v0[1], v0[2], v0[3], v1[0], v1[1], v1[2], v1[3]};
      if constexpr (EPI == 0) {
        bf16x8 o;
        #pragma unroll
        for (int k = 0; k < 8; ++k) o[k] = f2bf(v[k]);
        *(bf16x8*)(Obf + rg * ldOut + (ncol0 + c0)) = o;
      } else if constexpr (EPI == 2) {
        bf16x8 o;
        #pragma unroll
        for (int k = 0; k < 8; ++k) o[k] = f2bf(fmaxf(v[k] + s_bias[c0 + k], 0.f));
        *(bf16x8*)(Obf + rg * 256 + c0) = o;
      } else {  // EPI == 4: h_new = 2*h + (acc + bias)
        f32x4 h0 = *(const f32x4*)(Hf + rg * 256 + c0);
        f32x4 h1 = *(const f32x4*)(Hf + rg * 256 + c0 + 4);
        float hh[8] = {h0[0], h0[1], h0[2], h0[3], h1[0], h1[1], h1[2], h1[3]};
        bf16x8 o; f32x4 n0, n1;
        #pragma unroll
        for (int k = 0; k < 8; ++k) {
          float hn = 2.f * hh[k] + v[k] + s_bias[c0 + k];
          o[k] = f2bf(hn);
          if (k < 4) n0[k] = hn; else n1[k - 4] = hn;
        }
        *(f32x4*)(Hf + rg * 256 + c0)     = n0;
        *(f32x4*)(Hf + rg * 256 + c0 + 4) = n1;
        *(bf16x8*)(Hbf + rg * 256 + c0) = o;
      }
    }
  }
}

// ---------------------------------------------------------------------------
// Fused edge pipeline v4: 80 edges (= 4 whole nodes) per block, 4096 blocks.
// Occupancy-first redesign: no LDS B-staging region, no Prc window — just
// the m1 tile (40 KB) + small statics => ~45 KB LDS = 3 blocks/CU (12 waves,
// +50% vs r6-r9), and only THREE barriers per block.
//  * gauss tile built cooperatively (2.5 exps/thread), overlaid in m1 region
//  * GEMM1 transposed (D[feat][edge]) so phase-2 writes m1 directly as
//    swizzled bf16x4 (no bridge)  [r7/r8-verified layout]
//  * Prc gathers 8B from global (L3-resident, hidden by 12 waves)
//  * We2T B-frags global->VGPR per kc (L2-hot)
//  * register relu+segsum epilogue (r5-verified)
// ---------------------------------------------------------------------------
__global__ void __launch_bounds__(256, 3)
edge_fused(const bf16* WgT_l, const bf16* We2T_l, const float* off,
           const float* pos, const int* eidx, const bf16* Prc,
           const float* be1, const float* wrad, const float* be2, bf16* Agg)
{
  __shared__ __align__(16) char smem[40960];   // m1 [80][512B]; gauss tile overlays
  __shared__ int   s_row[80];
  __shared__ int   s_col[80];
  __shared__ float s_rad[80];
  __shared__ float s_dist[80];
  __shared__ float s_b1[256];
  __shared__ float s_wr[256];
  __shared__ float s_off[64];

  const int tid  = threadIdx.x;
  const int w    = tid >> 6;
  const int lane = tid & 63;
  const int q    = lane >> 4;
  const int t16  = lane & 15;
  const int erow0 = blockIdx.x * 80;

  // GEMM1 A-fragments (WgT[feature][g]) — L2-hot global loads, early issue
  bf16x8 wgf[4][2];
  #pragma unroll
  for (int fi = 0; fi < 4; ++fi)
    #pragma unroll
    for (int ks = 0; ks < 2; ++ks) {
      int feat = 64 * w + 16 * fi + t16;
      wgf[fi][ks] = *(const bf16x8*)(WgT_l + (size_t)feat * 64 + (q + 4 * ks) * 8);
    }

  if (tid < 80) {
    int e = erow0 + tid;
    int r = eidx[e], c = eidx[ETOT + e];
    float dx = pos[c * 3 + 0] - pos[r * 3 + 0];
    float dy = pos[c * 3 + 1] - pos[r * 3 + 1];
    float dz = pos[c * 3 + 2] - pos[r * 3 + 2];
    float d2 = dx * dx + dy * dy + dz * dz;
    s_row[tid] = r; s_col[tid] = c;
    s_rad[tid]  = 0.01f * d2;                // (ANG_TO_NM)^2 * |dvec|^2
    s_dist[tid] = sqrtf(d2);
  }
  if (tid < 64) s_off[tid] = off[tid];
  s_b1[tid] = be1[tid];
  s_wr[tid] = wrad[tid];
  float b2v[4];
  #pragma unroll
  for (int ni = 0; ni < 4; ++ni) b2v[ni] = be2[64 * w + 16 * ni + t16];
  __syncthreads();                           // (#1) meta ready

  // cooperative gauss tile [80 e][8 oct] bf16x8, swizzled, at m1 base
  {
    const float GC = -0.5f / ((5.0f / 63.0f) * (5.0f / 63.0f));
    for (int idx = tid; idx < 640; idx += 256) {
      int e = idx >> 3, oct = idx & 7;
      float d = s_dist[e];
      bf16x8 v;
      #pragma unroll
      for (int j = 0; j < 8; ++j) {
        float t = d - s_off[oct * 8 + j];
        v[j] = f2bf(__expf(GC * t * t));
      }
      int f = e * 8 + (oct ^ (e & 7));
      *(bf16x8*)(smem + f * 16) = v;
    }
  }
  __syncthreads();                           // (#2) gauss tile ready

  // ---- Phase 1: GEMM1 transposed D[feature][edge], K=64 ----
  f32x4 acc1[4][5] = {};
  #pragma unroll
  for (int ks = 0; ks < 2; ++ks) {
    const int ko = q + 4 * ks;
    bf16x8 gv[5];
    #pragma unroll
    for (int ci = 0; ci < 5; ++ci) {
      int e = 16 * ci + t16;
      int f = e * 8 + (ko ^ (e & 7));
      gv[ci] = *(const bf16x8*)(smem + f * 16);
    }
    #pragma unroll
    for (int fi = 0; fi < 4; ++fi)
      #pragma unroll
      for (int ci = 0; ci < 5; ++ci)
        acc1[fi][ci] = __builtin_amdgcn_mfma_f32_16x16x32_bf16(
            wgf[fi][ks], gv[ci], acc1[fi][ci], 0, 0, 0);
  }
  __syncthreads();                           // (#3) gauss reads done -> overwrite ok

  // ---- Phase 2: epilogue -> m1 LDS tile (direct bf16x4, no bridge) ----
  #pragma unroll
  for (int ci = 0; ci < 5; ++ci) {
    int e = 16 * ci + t16;
    int er = s_row[e], ec = s_col[e];
    float rad = s_rad[e];
    #pragma unroll
    for (int fi = 0; fi < 4; ++fi) {
      int fb = 64 * w + 16 * fi + 4 * q;
      f32x4 tb = *(const f32x4*)(s_b1 + fb);
      f32x4 tw = *(const f32x4*)(s_wr + fb);
      bf16x4 pr = *(const bf16x4*)(Prc + (size_t)er * 512 + fb);
      bf16x4 pc = *(const bf16x4*)(Prc + (size_t)ec * 512 + 256 + fb);
      bf16x4 o;
      #pragma unroll
      for (int r = 0; r < 4; ++r) {
        float val = acc1[fi][ci][r] + tb[r] + rad * tw[r]
                  + bf2f(pr[r]) + bf2f(pc[r]);
        o[r] = f2bf(fmaxf(val, 0.f));
      }
      int u = (16 * w + 4 * fi + q) ^ (e & 14);
      *(bf16x4*)(smem + e * 512 + u * 8) = o;
    }
  }
  __syncthreads();                           // (#4) m1 complete

  // ---- Phase 3: GEMM2 (K=256), A = LDS m1, B = We2T global (L2-hot) ----
  f32x4 acc2[5][4] = {};
  #pragma unroll
  for (int kc = 0; kc < 4; ++kc) {
    bf16x8 bv[4][2];
    #pragma unroll
    for (int ni = 0; ni < 4; ++ni)
      #pragma unroll
      for (int ks = 0; ks < 2; ++ks) {
        int n = 64 * w + 16 * ni + t16;
        bv[ni][ks] = *(const bf16x8*)(We2T_l + (size_t)n * 256 + kc * 64 +
                                      (q + 4 * ks) * 8);
      }
    #pragma unroll
    for (int ks = 0; ks < 2; ++ks) {
      const int ko = q + 4 * ks;
      bf16x8 av[5];
      #pragma unroll
      for (int mi = 0; mi < 5; ++mi) {
        int e = 16 * mi + t16;
        int ub = (2 * (8 * kc + ko)) ^ (t16 & 14);
        av[mi] = *(const bf16x8*)(smem + e * 512 + ub * 8);
      }
      #pragma unroll
      for (int mi = 0; mi < 5; ++mi)
        #pragma unroll
        for (int ni = 0; ni < 4; ++ni)
          acc2[mi][ni] = __builtin_amdgcn_mfma_f32_16x16x32_bf16(
              av[mi], bv[ni][ks], acc2[mi][ni], 0, 0, 0);
    }
  }

  // ---- Phase 4: register relu + segment-sum -> Agg (r5-verified) ----
  #pragma unroll
  for (int ni = 0; ni < 4; ++ni) {
    float b = b2v[ni];
    float pp[5];
    #pragma unroll
    for (int mi = 0; mi < 5; ++mi) {
      float s = 0.f;
      #pragma unroll
      for (int r = 0; r < 4; ++r) s += fmaxf(acc2[mi][ni][r] + b, 0.f);
      pp[mi] = s;
    }
    #pragma unroll
    for (int nn = 0; nn < 4; ++nn) {        // node nn: groups g in [5nn, 5nn+4]
      float s = 0.f;
      #pragma unroll
      for (int mi = 0; mi < 5; ++mi) {
        int g = 4 * mi + q;
        if (g >= 5 * nn && g <= 5 * nn + 4) s += pp[mi];
      }
      s += __shfl_xor(s, 16, 64);
      s += __shfl_xor(s, 32, 64);
      if (q == nn)
        Agg[((size_t)blockIdx.x * 4 + nn) * 256 + 64 * w + 16 * ni + t16] =
            __float2bfloat16(s);
    }
  }
}

// ---------------------------------------------------------------------------
// Prep kernels: weight repack/transpose to bf16 [n][k] layouts, once per call
// ---------------------------------------------------------------------------
__global__ void wrct_kernel(const float* We1, bf16* WrcT) {
  int idx = blockIdx.x * 256 + threadIdx.x;         // L*512*256
  int k = idx & 255, np = (idx >> 8) & 511, l = idx >> 17;
  float v = (np < 256)
      ? We1[((size_t)l * 577 + k) * 256 + np]
      : We1[((size_t)l * 577 + 256 + k) * 256 + (np - 256)];
  WrcT[idx] = __float2bfloat16(v);
}
__global__ void wgt_kernel(const float* We1, bf16* WgT) {
  int idx = blockIdx.x * 256 + threadIdx.x;         // L*256*64
  int k = idx & 63, n = (idx >> 6) & 255, l = idx >> 14;
  WgT[idx] = __float2bfloat16(We1[((size_t)l * 577 + 513 + k) * 256 + n]);
}
__global__ void wrad_kernel(const float* We1, float* wrad) {
  int idx = blockIdx.x * 256 + threadIdx.x;         // L*256
  int n = idx & 255, l = idx >> 8;
  wrad[idx] = We1[((size_t)l * 577 + 512) * 256 + n];
}
__global__ void trans_kernel(const float* src, bf16* dst, int R, int C) {
  int idx = blockIdx.x * 256 + threadIdx.x;         // L*C*R, dst [l][n][k]
  int k = idx % R, rest = idx / R;
  int n = rest % C, l = rest / C;
  dst[idx] = __float2bfloat16(src[((size_t)l * R + k) * C + n]);
}

__global__ void h0_kernel(const int* types, const float* emb, float* h, bf16* hbf) {
  int i = blockIdx.x, c = threadIdx.x;
  float v = emb[(size_t)(types[i] - 1) * 256 + c];
  h[(size_t)i * 256 + c] = v;
  hbf[(size_t)i * 256 + c] = __float2bfloat16(v);
}

// global mean pool over 32 atoms per building block
__global__ void pool_kernel(const float* h, float* out) {
  int b = blockIdx.x, c = threadIdx.x;
  float s = 0.f;
  #pragma unroll
  for (int j = 0; j < 32; ++j) s += h[((size_t)b * 32 + j) * 256 + c];
  out[(size_t)b * 256 + c] = s * (1.0f / 32.0f);
}

// ---------------------------------------------------------------------------
extern "C" void kernel_launch(void* const* d_in, const int* in_sizes, int n_in,
                              void* d_out, int out_size, void* d_ws, size_t ws_size,
                              hipStream_t stream) {
  const float* pos   = (const float*)d_in[0];
  const int*   atype = (const int*)  d_in[1];
  const int*   eidx  = (const int*)  d_in[2];
  const float* emb   = (const float*)d_in[4];
  const float* off   = (const float*)d_in[5];
  const float* We1   = (const float*)d_in[6];
  const float* be1   = (const float*)d_in[7];
  const float* We2   = (const float*)d_in[8];
  const float* be2   = (const float*)d_in[9];
  const float* Wn1   = (const float*)d_in[10];
  const float* bn1   = (const float*)d_in[11];
  const float* Wn2   = (const float*)d_in[12];
  const float* bn2   = (const float*)d_in[13];
  float* out = (float*)d_out;

  // ---- workspace carve (256B aligned, ~61 MB total; ws_size = 256 MiB) ----
  size_t o = 0;
  auto carve = [&](size_t bytes) {
    void* p = (char*)d_ws + o;
    o += (bytes + 255) & ~(size_t)255;
    return p;
  };
  float* h     = (float*)carve((size_t)NATOMS * 256 * 4);   // 16 MB
  bf16*  hbf   = (bf16*) carve((size_t)NATOMS * 256 * 2);   //  8 MB
  bf16*  Prc   = (bf16*) carve((size_t)NATOMS * 512 * 2);   // 16 MB
  bf16*  aggbf = (bf16*) carve((size_t)NATOMS * 256 * 2);   //  8 MB (agg, then nMLP1 out)
  bf16*  WrcT  = (bf16*) carve((size_t)NLAYER * 512 * 256 * 2);
  bf16*  WgT   = (bf16*) carve((size_t)NLAYER * 256 * 64 * 2);
  bf16*  We2T  = (bf16*) carve((size_t)NLAYER * 256 * 256 * 2);
  bf16*  Wn1T  = (bf16*) carve((size_t)NLAYER * 256 * 512 * 2);
  bf16*  Wn2T  = (bf16*) carve((size_t)NLAYER * 256 * 256 * 2);
  float* wradp = (float*)carve((size_t)NLAYER * 256 * 4);

  // ---- prep: weights -> bf16 transposed, h0 gather ----
  wrct_kernel<<<2048, 256, 0, stream>>>(We1, WrcT);
  wgt_kernel <<< 256, 256, 0, stream>>>(We1, WgT);
  wrad_kernel<<<   4, 256, 0, stream>>>(We1, wradp);
  trans_kernel<<<1024, 256, 0, stream>>>(We2, We2T, 256, 256);
  trans_kernel<<<2048, 256, 0, stream>>>(Wn1, Wn1T, 512, 256);
  trans_kernel<<<1024, 256, 0, stream>>>(Wn2, Wn2T, 256, 256);
  h0_kernel  <<<NATOMS, 256, 0, stream>>>(atype, emb, h, hbf);

  // ---- layers ----
  for (int l = 0; l < NLAYER; ++l) {
    // Prc[N,512] = h @ [We1_r | We1_c]
    gemm_k<256, 0, 64><<<dim3(256, 2), 256, 0, stream>>>(
        hbf, nullptr, WrcT + (size_t)l * 512 * 256, Prc, 512, nullptr,
        nullptr, nullptr);
    // agg = segment_sum(relu(MLP2(MLP1(edges)))) — m1 never leaves LDS
    edge_fused<<<ETOT / 80, 256, 0, stream>>>(
        WgT + (size_t)l * 256 * 64, We2T + (size_t)l * 256 * 256, off, pos,
        eidx, Prc, be1 + l * 256, wradp + l * 256, be2 + l * 256, aggbf);
    // t[N,256] = relu([h|agg] @ Wn1 + bn1), in-place into aggbf
    gemm_k<512, 2, 64><<<dim3(256, 1), 256, 0, stream>>>(
        hbf, aggbf, Wn1T + (size_t)l * 256 * 512, aggbf, 256, bn1 + l * 256,
        nullptr, nullptr);
    // h = 2h + (t @ Wn2 + bn2)
    gemm_k<256, 4, 64><<<dim3(256, 1), 256, 0, stream>>>(
        aggbf, nullptr, Wn2T + (size_t)l * 256 * 256, nullptr, 0, bn2 + l * 256,
        h, hbf);
  }

  pool_kernel<<<512, 256, 0, stream>>>(h, out);
}

// Round 11
// 602.168 us; speedup vs baseline: 1.4670x; 1.2647x over previous
//
#include <hip/hip_runtime.h>
#include <hip/hip_bf16.h>
#include <stdint.h>

// Problem constants (fixed by reference setup)
#define NATOMS 16384          // B*NPB = 512*32
#define ETOT   327680         // NATOMS*K (K=20 neighbors)
#define NLAYER 4

typedef __hip_bfloat16 bf16;
using bf16x8 = __attribute__((ext_vector_type(8))) short;   // MFMA A/B frag (4 VGPRs)
using bf16x4 = __attribute__((ext_vector_type(4))) short;   // 8B packed bf16
using f32x4  = __attribute__((ext_vector_type(4))) float;   // MFMA C/D frag

#define LDSF_STRIDE 260   // f32 words per barrier-bridge row (gemm_k)

__device__ __forceinline__ float bf2f(short s) {
  union { float f; unsigned u; } x; x.u = ((unsigned)(unsigned short)s) << 16; return x.f;
}
__device__ __forceinline__ short f2bf(float f) {
  bf16 b = __float2bfloat16(f);
  return *(short*)&b;
}

// ---------------------------------------------------------------------------
// async global->LDS 16B (used by gemm_k only)
// ---------------------------------------------------------------------------
__device__ __forceinline__ void async16(const void* g, void* l) {
  __builtin_amdgcn_global_load_lds(
      (const __attribute__((address_space(1))) unsigned int*)g,
      (__attribute__((address_space(3))) unsigned int*)l, 16, 0, 0);
}

// ---------------------------------------------------------------------------
// Tiled bf16 MFMA GEMM: C[MT x 256] per block, 4 waves (64 cols each),
// K in chunks of 64.  MT in {64,128}.  (unchanged from round 5)
// ---------------------------------------------------------------------------
template<int KTOT, int EPI, int MT>
__global__ void __launch_bounds__(256, 2)
gemm_k(const bf16* A, const bf16* A2, const bf16* B,
       bf16* Obf, int ldOut, const float* bias,
       float* Hf, bf16* Hbf)
{
  __shared__ __align__(16) char smem[49152];   // A tile @0 (<=16KB), B tile 32KB @16384
  __shared__ float s_bias[256];

  const int tid  = threadIdx.x;
  const int w    = tid >> 6;        // wave 0..3 (owns 64-col slice)
  const int lane = tid & 63;
  const int q    = lane >> 4;       // quad
  const int t16  = lane & 15;
  const size_t row0 = (size_t)blockIdx.x * MT;
  const int ncol0 = blockIdx.y * 256;
  constexpr int MI = MT / 16;       // row-tiles per wave
  constexpr int AI = MT / 32;       // A-stage issues per wave

  if constexpr (EPI == 2 || EPI == 4) s_bias[tid] = bias[tid];

  f32x4 acc[MI][4] = {};

  constexpr int NCHUNK = KTOT / 64;
  for (int kc = 0; kc < NCHUNK; ++kc) {
    const int k0 = kc * 64;
    const bf16* Asrc; int k0e; int ldA;
    if constexpr (KTOT == 512) {            // node MLP1: concat [h | agg]
      if (k0 < 256) { Asrc = A;  k0e = k0;       }
      else          { Asrc = A2; k0e = k0 - 256; }
      ldA = 256;
    } else {
      Asrc = A; k0e = k0; ldA = KTOT;
    }

    __syncthreads();
    #pragma unroll
    for (int ii = 0; ii < AI; ++ii) {
      int i = w * AI + ii;
      int f = i * 64 + lane;
      int m = f >> 3, s = f & 7;
      int ko = s ^ (m & 7);
      const bf16* g = Asrc + (row0 + (size_t)m) * ldA + (size_t)(k0e + ko * 8);
      async16(g, smem + i * 1024);
    }
    #pragma unroll
    for (int ii = 0; ii < 8; ++ii) {
      int i = w * 8 + ii;
      int f = i * 64 + lane;
      int n = f >> 3, s = f & 7;
      int ko = s ^ (n & 7);
      const bf16* g = B + (size_t)(ncol0 + n) * KTOT + (size_t)(k0 + ko * 8);
      async16(g, smem + 16384 + i * 1024);
    }
    __syncthreads();

    #pragma unroll
    for (int ks = 0; ks < 2; ++ks) {
      bf16x8 av[MI]; bf16x8 bv[4];
      const int ko = q + 4 * ks;
      #pragma unroll
      for (int mi = 0; mi < MI; ++mi) {
        int m = 16 * mi + t16;
        int f = m * 8 + (ko ^ (m & 7));
        av[mi] = *(const bf16x8*)(smem + f * 16);
      }
      #pragma unroll
      for (int ni = 0; ni < 4; ++ni) {
        int n = 64 * w + 16 * ni + t16;
        int f = n * 8 + (ko ^ (n & 7));
        bv[ni] = *(const bf16x8*)(smem + 16384 + f * 16);
      }
      #pragma unroll
      for (int mi = 0; mi < MI; ++mi)
        #pragma unroll
        for (int ni = 0; ni < 4; ++ni)
          acc[mi][ni] = __builtin_amdgcn_mfma_f32_16x16x32_bf16(
              av[mi], bv[ni], acc[mi][ni], 0, 0, 0);
    }
  }

  // ---- epilogue via LDS transpose bridge ----
  float* lds_f = (float*)smem;
  #pragma unroll
  for (int mi = 0; mi < MI; ++mi) {
    __syncthreads();
    #pragma unroll
    for (int ni = 0; ni < 4; ++ni)
      #pragma unroll
      for (int r = 0; r < 4; ++r)
        lds_f[(4 * q + r) * LDSF_STRIDE + 64 * w + 16 * ni + t16] = acc[mi][ni][r];
    __syncthreads();
    #pragma unroll
    for (int j = 0; j < 2; ++j) {
      int task = tid + 256 * j;
      int rr = task >> 5, cg = task & 31;
      int c0 = cg * 8;
      size_t rg = row0 + 16 * mi + rr;
      f32x4 v0 = *(const f32x4*)(lds_f + rr * LDSF_STRIDE + c0);
      f32x4 v1 = *(const f32x4*)(lds_f + rr * LDSF_STRIDE + c0 + 4);
      float v[8] = {v0[0], v0[1], v0[2], v0[3], v1[0], v1[1], v1[2], v1[3]};
      if constexpr (EPI == 0) {
        bf16x8 o;
        #pragma unroll
        for (int k = 0; k < 8; ++k) o[k] = f2bf(v[k]);
        *(bf16x8*)(Obf + rg * ldOut + (ncol0 + c0)) = o;
      } else if constexpr (EPI == 2) {
        bf16x8 o;
        #pragma unroll
        for (int k = 0; k < 8; ++k) o[k] = f2bf(fmaxf(v[k] + s_bias[c0 + k], 0.f));
        *(bf16x8*)(Obf + rg * 256 + c0) = o;
      } else {  // EPI == 4: h_new = 2*h + (acc + bias)
        f32x4 h0 = *(const f32x4*)(Hf + rg * 256 + c0);
        f32x4 h1 = *(const f32x4*)(Hf + rg * 256 + c0 + 4);
        float hh[8] = {h0[0], h0[1], h0[2], h0[3], h1[0], h1[1], h1[2], h1[3]};
        bf16x8 o; f32x4 n0, n1;
        #pragma unroll
        for (int k = 0; k < 8; ++k) {
          float hn = 2.f * hh[k] + v[k] + s_bias[c0 + k];
          o[k] = f2bf(hn);
          if (k < 4) n0[k] = hn; else n1[k - 4] = hn;
        }
        *(f32x4*)(Hf + rg * 256 + c0)     = n0;
        *(f32x4*)(Hf + rg * 256 + c0 + 4) = n1;
        *(bf16x8*)(Hbf + rg * 256 + c0) = o;
      }
    }
  }
}

// ---------------------------------------------------------------------------
// Fused edge pipeline v5: 80 edges (= 4 nodes, bb-aligned) per block.
// TRANSACTION-COUNT redesign: every global access is coalesced.
//  * Wg / We2 pre-packed in MFMA-fragment order -> B loads are base+lane*16
//    (1 coalesced transaction vs 64-line gather).
//  * Prc P_c band (bb's 32 rows x cols 256..511, 16.5 KB) and P_r (block's
//    4 rows x cols 0..255, 2 KB) loaded coalesced into LDS once; phase-2
//    "gathers" become LDS reads.
//  * row node = e/20 identity (setup guarantees) -> no eidx row loads.
//  * owners (tid<80) compute their own gauss octets; waves 2,3 do window
//    loads concurrently; 3 barriers total.
// LDS: m1 40960 | winC 16896 (pitch 528) | winR 2112 | col 320 | rad 320
//    = 60608 -> 2 blocks/CU.
// ---------------------------------------------------------------------------
#define WINC 40960
#define WINR 57856
#define SCOL 59968
#define SRAD 60288
#define WPITCH 528

__global__ void __launch_bounds__(256, 2)
edge_fused(const bf16* Wgp_l, const bf16* W2p_l, const float* off,
           const float* pos, const int* eidx, const bf16* Prc,
           const float* be1, const float* wrad, const float* be2, bf16* Agg)
{
  __shared__ __align__(16) char smem[60608];
  int*   s_col = (int*)  (smem + SCOL);
  float* s_rad = (float*)(smem + SRAD);

  const int tid  = threadIdx.x;
  const int w    = tid >> 6;
  const int lane = tid & 63;
  const int q    = lane >> 4;
  const int t16  = lane & 15;
  const int blk  = blockIdx.x;
  const int node0  = (blk >> 3) * 32;      // bb base node
  const int rnode0 = blk * 4;              // this block's first row node
  const int ebase  = blk * 80;

  // GEMM1 A-fragments from packed Wg: coalesced base + lane*16
  bf16x8 wgf[4][2];
  #pragma unroll
  for (int fi = 0; fi < 4; ++fi)
    #pragma unroll
    for (int ks = 0; ks < 2; ++ks)
      wgf[fi][ks] = *(const bf16x8*)(Wgp_l + (size_t)(((fi * 2 + ks) * 4 + w) * 512)
                                     + lane * 8);

  // ---- P_c window: 32 rows x 512 B (cols 256..511), coalesced ----
  {
    int row = tid >> 3, seg = tid & 7;     // 64 B per thread
    const bf16* src = Prc + (size_t)(node0 + row) * 512 + 256 + seg * 32;
    char* dst = smem + WINC + row * WPITCH + seg * 64;
    #pragma unroll
    for (int j = 0; j < 4; ++j)
      *(bf16x8*)(dst + j * 16) = *(const bf16x8*)(src + j * 8);
  }
  // ---- P_r window: 4 rows x 512 B (cols 0..255), coalesced ----
  if (tid < 128) {
    int row = tid >> 5, seg = tid & 31;    // 16 B per thread
    *(bf16x8*)(smem + WINR + row * WPITCH + seg * 16) =
        *(const bf16x8*)(Prc + (size_t)(rnode0 + row) * 512 + seg * 8);
  }

  // ---- meta + gauss (owners); offsets read from global (uniform, L2-hot) --
  if (tid < 80) {
    int e = ebase + tid;
    int rg = rnode0 + tid / 20;            // row node = e/20 (setup identity)
    int cg = eidx[ETOT + e];
    float dx = pos[cg * 3 + 0] - pos[rg * 3 + 0];
    float dy = pos[cg * 3 + 1] - pos[rg * 3 + 1];
    float dz = pos[cg * 3 + 2] - pos[rg * 3 + 2];
    float d2 = dx * dx + dy * dy + dz * dz;
    s_col[tid] = cg & 31;
    s_rad[tid] = 0.01f * d2;
    float d = sqrtf(d2);
    const float GC = -0.5f / ((5.0f / 63.0f) * (5.0f / 63.0f));
    #pragma unroll
    for (int oct = 0; oct < 8; ++oct) {
      bf16x8 v;
      #pragma unroll
      for (int j = 0; j < 8; ++j) {
        float t = d - off[oct * 8 + j];
        v[j] = f2bf(__expf(GC * t * t));
      }
      int f = tid * 8 + (oct ^ (tid & 7));
      *(bf16x8*)(smem + f * 16) = v;
    }
  }
  __syncthreads();                         // (#1) windows + meta + gauss ready

  // ---- Phase 1: GEMM1 transposed D[feature][edge], K=64 ----
  f32x4 acc1[4][5] = {};
  #pragma unroll
  for (int ks = 0; ks < 2; ++ks) {
    const int ko = q + 4 * ks;
    bf16x8 gv[5];
    #pragma unroll
    for (int ci = 0; ci < 5; ++ci) {
      int e = 16 * ci + t16;
      int f = e * 8 + (ko ^ (e & 7));
      gv[ci] = *(const bf16x8*)(smem + f * 16);
    }
    #pragma unroll
    for (int fi = 0; fi < 4; ++fi)
      #pragma unroll
      for (int ci = 0; ci < 5; ++ci)
        acc1[fi][ci] = __builtin_amdgcn_mfma_f32_16x16x32_bf16(
            wgf[fi][ks], gv[ci], acc1[fi][ci], 0, 0, 0);
  }
  __syncthreads();                         // (#2) gauss reads done -> overwrite ok

  // ---- Phase 2: epilogue; P_r/P_c from LDS windows -> m1 tile ----
  {
    f32x4 tb[4], tw[4];
    #pragma unroll
    for (int fi = 0; fi < 4; ++fi) {
      int fb = 64 * w + 16 * fi + 4 * q;
      tb[fi] = *(const f32x4*)(be1 + fb);
      tw[fi] = *(const f32x4*)(wrad + fb);
    }
    #pragma unroll
    for (int ci = 0; ci < 5; ++ci) {
      int e = 16 * ci + t16;
      int rl = e / 20;                     // local row node 0..3
      int cl = s_col[e];
      float rad = s_rad[e];
      #pragma unroll
      for (int fi = 0; fi < 4; ++fi) {
        int fb = 64 * w + 16 * fi + 4 * q;
        bf16x4 pr = *(const bf16x4*)(smem + WINR + rl * WPITCH + fb * 2);
        bf16x4 pc = *(const bf16x4*)(smem + WINC + cl * WPITCH + fb * 2);
        bf16x4 o;
        #pragma unroll
        for (int r = 0; r < 4; ++r) {
          float val = acc1[fi][ci][r] + tb[fi][r] + rad * tw[fi][r]
                    + bf2f(pr[r]) + bf2f(pc[r]);
          o[r] = f2bf(fmaxf(val, 0.f));
        }
        int u = (16 * w + 4 * fi + q) ^ (e & 14);
        *(bf16x4*)(smem + e * 512 + u * 8) = o;
      }
    }
  }
  __syncthreads();                         // (#3) m1 complete

  // ---- Phase 3: GEMM2 (K=256), A = LDS m1, B = packed We2 (coalesced) ----
  f32x4 acc2[5][4] = {};
  #pragma unroll
  for (int kc = 0; kc < 4; ++kc) {
    bf16x8 bv[4][2];
    #pragma unroll
    for (int ni = 0; ni < 4; ++ni)
      #pragma unroll
      for (int ks = 0; ks < 2; ++ks) {
        int frag = kc * 8 + ks * 4 + ni;
        bv[ni][ks] = *(const bf16x8*)(W2p_l + (size_t)((frag * 4 + w) * 512)
                                      + lane * 8);
      }
    #pragma unroll
    for (int ks = 0; ks < 2; ++ks) {
      const int ko = q + 4 * ks;
      bf16x8 av[5];
      #pragma unroll
      for (int mi = 0; mi < 5; ++mi) {
        int e = 16 * mi + t16;
        int ub = (2 * (8 * kc + ko)) ^ (t16 & 14);
        av[mi] = *(const bf16x8*)(smem + e * 512 + ub * 8);
      }
      #pragma unroll
      for (int mi = 0; mi < 5; ++mi)
        #pragma unroll
        for (int ni = 0; ni < 4; ++ni)
          acc2[mi][ni] = __builtin_amdgcn_mfma_f32_16x16x32_bf16(
              av[mi], bv[ni][ks], acc2[mi][ni], 0, 0, 0);
    }
  }

  // ---- Phase 4: register relu + segment-sum -> Agg (r5-verified) ----
  #pragma unroll
  for (int ni = 0; ni < 4; ++ni) {
    float b = be2[64 * w + 16 * ni + t16];
    float pp[5];
    #pragma unroll
    for (int mi = 0; mi < 5; ++mi) {
      float s = 0.f;
      #pragma unroll
      for (int r = 0; r < 4; ++r) s += fmaxf(acc2[mi][ni][r] + b, 0.f);
      pp[mi] = s;
    }
    #pragma unroll
    for (int nn = 0; nn < 4; ++nn) {      // node nn: groups g in [5nn, 5nn+4]
      float s = 0.f;
      #pragma unroll
      for (int mi = 0; mi < 5; ++mi) {
        int g = 4 * mi + q;
        if (g >= 5 * nn && g <= 5 * nn + 4) s += pp[mi];
      }
      s += __shfl_xor(s, 16, 64);
      s += __shfl_xor(s, 32, 64);
      if (q == nn)
        Agg[(size_t)(rnode0 + nn) * 256 + 64 * w + 16 * ni + t16] =
            __float2bfloat16(s);
    }
  }
}

// ---------------------------------------------------------------------------
// Prep kernels
// ---------------------------------------------------------------------------
__global__ void wrct_kernel(const float* We1, bf16* WrcT) {
  int idx = blockIdx.x * 256 + threadIdx.x;         // L*512*256
  int k = idx & 255, np = (idx >> 8) & 511, l = idx >> 17;
  float v = (np < 256)
      ? We1[((size_t)l * 577 + k) * 256 + np]
      : We1[((size_t)l * 577 + 256 + k) * 256 + (np - 256)];
  WrcT[idx] = __float2bfloat16(v);
}
// packed Wg fragments: [l][fi*2+ks][w][lane][j]
__global__ void wgp_kernel(const float* We1, bf16* Wgp) {
  int idx = blockIdx.x * 256 + threadIdx.x;         // L*16384
  int i = idx & 16383, l = idx >> 14;
  int j = i & 7, lane = (i >> 3) & 63, w = (i >> 9) & 3, fr = i >> 11;
  int fi = fr >> 1, ks = fr & 1;
  int t16 = lane & 15, q = lane >> 4;
  int g = (q + 4 * ks) * 8 + j;
  int feat = 64 * w + 16 * fi + t16;
  Wgp[idx] = __float2bfloat16(We1[((size_t)l * 577 + 513 + g) * 256 + feat]);
}
// packed We2 fragments: [l][kc*8+ks*4+ni][w][lane][j]
__global__ void w2p_kernel(const float* We2, bf16* W2p) {
  int idx = blockIdx.x * 256 + threadIdx.x;         // L*65536
  int i = idx & 65535, l = idx >> 16;
  int j = i & 7, lane = (i >> 3) & 63, w = (i >> 9) & 3, fr = i >> 11;
  int ni = fr & 3, ks = (fr >> 2) & 1, kc = fr >> 3;
  int t16 = lane & 15, q = lane >> 4;
  int k = kc * 64 + (q + 4 * ks) * 8 + j;
  int n = 64 * w + 16 * ni + t16;
  W2p[idx] = __float2bfloat16(We2[((size_t)l * 256 + k) * 256 + n]);
}
__global__ void wrad_kernel(const float* We1, float* wrad) {
  int idx = blockIdx.x * 256 + threadIdx.x;         // L*256
  int n = idx & 255, l = idx >> 8;
  wrad[idx] = We1[((size_t)l * 577 + 512) * 256 + n];
}
__global__ void trans_kernel(const float* src, bf16* dst, int R, int C) {
  int idx = blockIdx.x * 256 + threadIdx.x;         // L*C*R, dst [l][n][k]
  int k = idx % R, rest = idx / R;
  int n = rest % C, l = rest / C;
  dst[idx] = __float2bfloat16(src[((size_t)l * R + k) * C + n]);
}

__global__ void h0_kernel(const int* types, const float* emb, float* h, bf16* hbf) {
  int i = blockIdx.x, c = threadIdx.x;
  float v = emb[(size_t)(types[i] - 1) * 256 + c];
  h[(size_t)i * 256 + c] = v;
  hbf[(size_t)i * 256 + c] = __float2bfloat16(v);
}

// global mean pool over 32 atoms per building block
__global__ void pool_kernel(const float* h, float* out) {
  int b = blockIdx.x, c = threadIdx.x;
  float s = 0.f;
  #pragma unroll
  for (int j = 0; j < 32; ++j) s += h[((size_t)b * 32 + j) * 256 + c];
  out[(size_t)b * 256 + c] = s * (1.0f / 32.0f);
}

// ---------------------------------------------------------------------------
extern "C" void kernel_launch(void* const* d_in, const int* in_sizes, int n_in,
                              void* d_out, int out_size, void* d_ws, size_t ws_size,
                              hipStream_t stream) {
  const float* pos   = (const float*)d_in[0];
  const int*   atype = (const int*)  d_in[1];
  const int*   eidx  = (const int*)  d_in[2];
  const float* emb   = (const float*)d_in[4];
  const float* off   = (const float*)d_in[5];
  const float* We1   = (const float*)d_in[6];
  const float* be1   = (const float*)d_in[7];
  const float* We2   = (const float*)d_in[8];
  const float* be2   = (const float*)d_in[9];
  const float* Wn1   = (const float*)d_in[10];
  const float* bn1   = (const float*)d_in[11];
  const float* Wn2   = (const float*)d_in[12];
  const float* bn2   = (const float*)d_in[13];
  float* out = (float*)d_out;

  // ---- workspace carve (256B aligned, ~61 MB total; ws_size = 256 MiB) ----
  size_t o = 0;
  auto carve = [&](size_t bytes) {
    void* p = (char*)d_ws + o;
    o += (bytes + 255) & ~(size_t)255;
    return p;
  };
  float* h     = (float*)carve((size_t)NATOMS * 256 * 4);   // 16 MB
  bf16*  hbf   = (bf16*) carve((size_t)NATOMS * 256 * 2);   //  8 MB
  bf16*  Prc   = (bf16*) carve((size_t)NATOMS * 512 * 2);   // 16 MB
  bf16*  aggbf = (bf16*) carve((size_t)NATOMS * 256 * 2);   //  8 MB (agg, then nMLP1 out)
  bf16*  WrcT  = (bf16*) carve((size_t)NLAYER * 512 * 256 * 2);
  bf16*  Wgp   = (bf16*) carve((size_t)NLAYER * 16384 * 2);
  bf16*  W2p   = (bf16*) carve((size_t)NLAYER * 65536 * 2);
  bf16*  Wn1T  = (bf16*) carve((size_t)NLAYER * 256 * 512 * 2);
  bf16*  Wn2T  = (bf16*) carve((size_t)NLAYER * 256 * 256 * 2);
  float* wradp = (float*)carve((size_t)NLAYER * 256 * 4);

  // ---- prep: weights -> bf16 transposed/packed, h0 gather ----
  wrct_kernel<<<2048, 256, 0, stream>>>(We1, WrcT);
  wgp_kernel <<< 256, 256, 0, stream>>>(We1, Wgp);
  w2p_kernel <<<1024, 256, 0, stream>>>(We2, W2p);
  wrad_kernel<<<   4, 256, 0, stream>>>(We1, wradp);
  trans_kernel<<<2048, 256, 0, stream>>>(Wn1, Wn1T, 512, 256);
  trans_kernel<<<1024, 256, 0, stream>>>(Wn2, Wn2T, 256, 256);
  h0_kernel  <<<NATOMS, 256, 0, stream>>>(atype, emb, h, hbf);

  // ---- layers ----
  for (int l = 0; l < NLAYER; ++l) {
    // Prc[N,512] = h @ [We1_r | We1_c]
    gemm_k<256, 0, 64><<<dim3(256, 2), 256, 0, stream>>>(
        hbf, nullptr, WrcT + (size_t)l * 512 * 256, Prc, 512, nullptr,
        nullptr, nullptr);
    // agg = segment_sum(relu(MLP2(MLP1(edges)))) — m1 never leaves LDS
    edge_fused<<<ETOT / 80, 256, 0, stream>>>(
        Wgp + (size_t)l * 16384, W2p + (size_t)l * 65536, off, pos,
        eidx, Prc, be1 + l * 256, wradp + l * 256, be2 + l * 256, aggbf);
    // t[N,256] = relu([h|agg] @ Wn1 + bn1), in-place into aggbf
    gemm_k<512, 2, 64><<<dim3(256, 1), 256, 0, stream>>>(
        hbf, aggbf, Wn1T + (size_t)l * 256 * 512, aggbf, 256, bn1 + l * 256,
        nullptr, nullptr);
    // h = 2h + (t @ Wn2 + bn2)
    gemm_k<256, 4, 64><<<dim3(256, 1), 256, 0, stream>>>(
        aggbf, nullptr, Wn2T + (size_t)l * 256 * 256, nullptr, 0, bn2 + l * 256,
        h, hbf);
  }

  pool_kernel<<<512, 256, 0, stream>>>(h, out);
}